// Round 18
// baseline (111.229 us; speedup 1.0000x reference)
//
#include <hip/hip_runtime.h>

// Trilinear interpolation of a 128^3 x 16 latent grid at 2M random points.
// 3-phase spatial counting sort; phase B = block-shared LDS tile.
//   A1: counting-sort points into 512 super-bins (16^3 cells); packed 16-B
//       tuples in d_out (fully overwritten by B afterwards).
//   A2: integer re-bin into 16 children (4x2x2 fine bins) -> 8192 fine bins
//       (4x8x8 cells each); 8-B packed tuples in d_ws.
//   B : one 512-THREAD block (8 waves) per fine bin; tile 5x9x9 = 405 rows
//       (28 KB) DMA-staged; 4 blocks/CU x 8 waves = 32 waves/CU (TLP attacks
//       the measured drain-latency stall of R16's 37%-occupancy version);
//       tuple prefetch BEFORE staging (T14); one __syncthreads; 4 lanes/point.

constexpr int   GRID_RES   = 128;
constexpr int   LATENT_DIM = 16;
constexpr float SCALE      = 126.0f;          // GRID_RES - 2
constexpr float WQ         = 4095.0f;
constexpr float WQI        = 1.0f / 4095.0f;
constexpr float WQI11      = 1.0f / 2047.0f;

constexpr int NSUPER    = 512;                 // 8x8x8 supers of 16^3 cells
constexpr int NCHILD    = 16;                  // 4x2x2 fine bins per super
constexpr int NFINE     = NSUPER * NCHILD;     // 8192 = 32x16x16 bins
constexpr int CAP_F     = 320;                 // mean 256, sigma ~16
constexpr int SPILL_CAP = 16384;
constexpr int NROWS     = 5 * 9 * 9;           // 405 staged latent rows
constexpr int NUNITS    = NROWS * 4;           // 1620 16-B units
constexpr int NXCD      = 8;

// d_ws layout
constexpr size_t SCUR_OFF     = 0;             // 512 u32
constexpr size_t FCUR_OFF     = 2048;          // 8192 u32
constexpr size_t SPILLCUR_OFF = 34816;         // 1 u32
constexpr size_t CUR_BYTES    = 36864;         // memset region
constexpr size_t FINE_OFF     = CUR_BYTES;
constexpr size_t FINE_BYTES   = (size_t)NFINE * CAP_F * 8;    // 21 MB
constexpr size_t SPILL_OFF    = FINE_OFF + FINE_BYTES;
constexpr size_t WS_NEEDED    = SPILL_OFF + (size_t)SPILL_CAP * 16;

typedef float    fvec4 __attribute__((ext_vector_type(4)));
typedef unsigned uvec4 __attribute__((ext_vector_type(4)));
typedef unsigned uvec2 __attribute__((ext_vector_type(2)));
typedef const __attribute__((address_space(1))) unsigned int* gptr_t;
typedef __attribute__((address_space(3))) unsigned int*       lptr_t;

// ---- packing -----------------------------------------------------------------
// super tuple (uvec4): w0 = idx | lx<<21 ; w1 = ly | lz<<7 | wx12<<14 ;
//                      w2 = wy12 | wz12<<12 ; w3 = 0
// fine tuple (uvec2):  lo = idx | cell8<<21 | (wz11&7)<<29 ;
//                      hi = wx12 | wy12<<12 | (wz11>>3)<<24
// cell8 = (lx&3)<<6 | (ly&7)<<3 | (lz&7)   (bin = 4x8x8 cells)

__device__ __forceinline__ uvec4 pack_super(float x, float y, float z, unsigned idx) {
    const float sx = x * SCALE, sy = y * SCALE, sz = z * SCALE;
    const float bxf = floorf(sx), byf = floorf(sy), bzf = floorf(sz);
    const int lx = min(max((int)bxf, 0), 125);
    const int ly = min(max((int)byf, 0), 125);
    const int lz = min(max((int)bzf, 0), 125);
    const unsigned wx = (unsigned)rintf((sx - bxf) * WQ);
    const unsigned wy = (unsigned)rintf((sy - byf) * WQ);
    const unsigned wz = (unsigned)rintf((sz - bzf) * WQ);
    uvec4 t;
    t.x = idx | ((unsigned)lx << 21);
    t.y = (unsigned)ly | ((unsigned)lz << 7) | (wx << 14);
    t.z = wy | (wz << 12);
    t.w = 0u;
    return t;
}

__device__ __forceinline__ int super_of_xyz(float x, float y, float z) {
    const int lx = min(max((int)floorf(x * SCALE), 0), 125);
    const int ly = min(max((int)floorf(y * SCALE), 0), 125);
    const int lz = min(max((int)floorf(z * SCALE), 0), 125);
    return ((lx >> 4) << 6) | ((ly >> 4) << 3) | (lz >> 4);   // [0,512)
}

__device__ __forceinline__ int child_of(const uvec4 t) {
    const int lx = (t.x >> 21) & 127, ly = t.y & 127, lz = (t.y >> 7) & 127;
    return (((lx >> 2) & 3) << 2) | (((ly >> 3) & 1) << 1) | ((lz >> 3) & 1);  // [0,16)
}

__device__ __forceinline__ uvec2 pack_fine(const uvec4 t) {
    const int lx = (t.x >> 21) & 127, ly = t.y & 127, lz = (t.y >> 7) & 127;
    const unsigned cell = ((unsigned)(lx & 3) << 6) | ((unsigned)(ly & 7) << 3)
                        | (unsigned)(lz & 7);
    const unsigned wx = (t.y >> 14) & 4095u;
    const unsigned wy = t.z & 4095u;
    const unsigned wz12 = (t.z >> 12) & 4095u;
    const unsigned wz11 = min((wz12 + 1u) >> 1, 2047u);
    uvec2 f;
    f.x = (t.x & 0x1FFFFFu) | (cell << 21) | ((wz11 & 7u) << 29);
    f.y = wx | (wy << 12) | ((wz11 >> 3) << 24);
    return f;
}

// ---- shared helpers (spill/fallback trilerp) ----------------------------------

__device__ __forceinline__ void corner_setup(
    float sx, float sy, float sz,
    int cx[2], int cy[2], int cz[2],
    float fx[2], float fy[2], float fz[2])
{
    const float bx = floorf(sx), by = floorf(sy), bz = floorf(sz);
    const int ix = (int)bx, iy = (int)by, iz = (int)bz;
    const float wbx = sx - bx, wby = sy - by, wbz = sz - bz;
    cx[0] = min(max(ix,     0), GRID_RES - 1);
    cx[1] = min(max(ix + 1, 0), GRID_RES - 1);
    cy[0] = min(max(iy,     0), GRID_RES - 1);
    cy[1] = min(max(iy + 1, 0), GRID_RES - 1);
    cz[0] = min(max(iz,     0), GRID_RES - 1);
    cz[1] = min(max(iz + 1, 0), GRID_RES - 1);
    fx[0] = 1.0f - wbx; fx[1] = wbx;
    fy[0] = 1.0f - wby; fy[1] = wby;
    fz[0] = 1.0f - wbz; fz[1] = wbz;
}

__device__ __forceinline__ fvec4 trilerp_q(
    const float* __restrict__ latents,
    const int cx[2], const int cy[2], const int cz[2],
    const float fx[2], const float fy[2], const float fz[2], int q)
{
    fvec4 acc = (fvec4)(0.0f);
    #pragma unroll
    for (int ox = 0; ox < 2; ++ox)
      #pragma unroll
      for (int oy = 0; oy < 2; ++oy)
        #pragma unroll
        for (int oz = 0; oz < 2; ++oz) {
            const int flat = cx[ox] * (GRID_RES * GRID_RES) + cy[oy] * GRID_RES + cz[oz];
            const float w = fx[ox] * fy[oy] * fz[oz];
            const fvec4 f = *reinterpret_cast<const fvec4*>(
                latents + (size_t)flat * LATENT_DIM + q * 4);
            acc += w * f;
        }
    return acc;
}

// ---- A1: counting-sort into 512 super-bins (packed segments in d_out) -------

__global__ __launch_bounds__(256) void binA1(
    const float* __restrict__ pts, int n_pts,
    unsigned* __restrict__ scur, uvec4* __restrict__ superSeg, int cap_s,
    unsigned* __restrict__ spillcur, uvec4* __restrict__ spillSeg)
{
    __shared__ unsigned cnt[NSUPER], base[NSUPER], off[NSUPER];
    const int t = threadIdx.x;
    for (int i = t; i < NSUPER; i += 256) { cnt[i] = 0; off[i] = 0; }
    __syncthreads();

    int chunk = (n_pts + gridDim.x - 1) / gridDim.x;
    chunk = (chunk + 3) & ~3;                      // multiple of 4
    const int lo = blockIdx.x * chunk;
    const int hi = min(lo + chunk, n_pts);

    // ---- count pass (4 pts / thread, coalesced float4 loads) ----------------
    for (int p4 = lo + t * 4; p4 < hi; p4 += 1024) {
        if (p4 + 4 <= hi) {
            const fvec4 a = *reinterpret_cast<const fvec4*>(pts + (size_t)p4 * 3);
            const fvec4 b = *reinterpret_cast<const fvec4*>(pts + (size_t)p4 * 3 + 4);
            const fvec4 c = *reinterpret_cast<const fvec4*>(pts + (size_t)p4 * 3 + 8);
            atomicAdd(&cnt[super_of_xyz(a.x, a.y, a.z)], 1u);
            atomicAdd(&cnt[super_of_xyz(a.w, b.x, b.y)], 1u);
            atomicAdd(&cnt[super_of_xyz(b.z, b.w, c.x)], 1u);
            atomicAdd(&cnt[super_of_xyz(c.y, c.z, c.w)], 1u);
        } else {
            for (int p = p4; p < hi; ++p)
                atomicAdd(&cnt[super_of_xyz(pts[3*p], pts[3*p+1], pts[3*p+2])], 1u);
        }
    }
    __syncthreads();
    for (int i = t; i < NSUPER; i += 256) base[i] = atomicAdd(&scur[i], cnt[i]);
    __syncthreads();

    // ---- scatter pass -------------------------------------------------------
    auto emit = [&](float x, float y, float z, int p) {
        const int s = super_of_xyz(x, y, z);
        const unsigned slot = base[s] + atomicAdd(&off[s], 1u);
        const uvec4 tp = pack_super(x, y, z, (unsigned)p);
        if (slot < (unsigned)cap_s) {
            superSeg[(size_t)s * cap_s + slot] = tp;
        } else {
            const unsigned sp = atomicAdd(spillcur, 1u);
            if (sp < (unsigned)SPILL_CAP) spillSeg[sp] = tp;
        }
    };
    for (int p4 = lo + t * 4; p4 < hi; p4 += 1024) {
        if (p4 + 4 <= hi) {
            const fvec4 a = *reinterpret_cast<const fvec4*>(pts + (size_t)p4 * 3);
            const fvec4 b = *reinterpret_cast<const fvec4*>(pts + (size_t)p4 * 3 + 4);
            const fvec4 c = *reinterpret_cast<const fvec4*>(pts + (size_t)p4 * 3 + 8);
            emit(a.x, a.y, a.z, p4);
            emit(a.w, b.x, b.y, p4 + 1);
            emit(b.z, b.w, c.x, p4 + 2);
            emit(c.y, c.z, c.w, p4 + 3);
        } else {
            for (int p = p4; p < hi; ++p)
                emit(pts[3*p], pts[3*p+1], pts[3*p+2], p);
        }
    }
}

// ---- A2: integer re-bin into 16 children; write 8-B packed tuples -----------

__global__ __launch_bounds__(256) void binA2(
    const uvec4* __restrict__ superSeg, int cap_s,
    const unsigned* __restrict__ scur,
    unsigned* __restrict__ fcur, uvec2* __restrict__ fineSeg,
    unsigned* __restrict__ spillcur, uvec4* __restrict__ spillSeg)
{
    constexpr int SLICES = 4;
    const int super = blockIdx.x / SLICES;
    const int slice = blockIdx.x % SLICES;
    const unsigned n = min(scur[super], (unsigned)cap_s);
    const unsigned lo = (unsigned)(((unsigned long long)n * slice) / SLICES);
    const unsigned hi = (unsigned)(((unsigned long long)n * (slice + 1)) / SLICES);

    __shared__ unsigned cnt[NCHILD], base[NCHILD], off[NCHILD];
    const int t = threadIdx.x;
    if (t < NCHILD) { cnt[t] = 0; off[t] = 0; }
    __syncthreads();

    for (unsigned i = lo + t; i < hi; i += 256) {
        const uvec4 tp = superSeg[(size_t)super * cap_s + i];
        atomicAdd(&cnt[child_of(tp)], 1u);
    }
    __syncthreads();
    if (t < NCHILD) base[t] = atomicAdd(&fcur[super * NCHILD + t], cnt[t]);
    __syncthreads();
    for (unsigned i = lo + t; i < hi; i += 256) {
        const uvec4 tp = superSeg[(size_t)super * cap_s + i];
        const int c = child_of(tp);
        const unsigned slot = base[c] + atomicAdd(&off[c], 1u);
        if (slot < (unsigned)CAP_F) {
            fineSeg[(size_t)(super * NCHILD + c) * CAP_F + slot] = pack_fine(tp);
        } else {
            const unsigned sp = atomicAdd(spillcur, 1u);
            if (sp < (unsigned)SPILL_CAP) spillSeg[sp] = tp;
        }
    }
}

// ---- B: one 512-thread block (8 waves) per fine bin; shared 5x9x9 tile ------
// 16-B unit u = rr*4 + ((q - rr) & 3); staging writes quarter qs=(j+r)&3 at
// unit (r,j) (inverse). rr = dx*81 + dy*9 + dz (z fastest -> 576-B runs).
// 28 KB LDS x 4 blocks/CU x 8 waves = 32 waves/CU (full TLP).

__global__ __launch_bounds__(512, 8) void binB(
    const uvec2* __restrict__ fineSeg, const unsigned* __restrict__ fcur,
    const float* __restrict__ latents, float* __restrict__ out)
{
    __shared__ __align__(16) float lat[1792 * 4];   // 28 KB (1620 units + pad)

    const int orig = blockIdx.x;                    // 8192 blocks
    const int fid  = (orig & (NXCD - 1)) * (NFINE / NXCD) + (orig >> 3);

    const int t    = threadIdx.x;                   // [0,512)
    const int wave = t >> 6;
    const int q    = t & 3, g = t >> 2;             // q: quarter, g: point slot [0,128)

    const int s = fid >> 4, c = fid & 15;
    const int fbx = (((s >> 6) & 7) << 2) | ((c >> 2) & 3);   // [0,32)
    const int fby = (((s >> 3) & 7) << 1) | ((c >> 1) & 1);   // [0,16)
    const int fbz = ((s & 7) << 1)        | (c & 1);          // [0,16)
    const int gx0 = fbx * 4, gy0 = fby * 8, gz0 = fbz * 8;

    const int n = (int)min(fcur[fid], (unsigned)CAP_F);   // n <= 320 = 3*128 - 64
    if (n == 0) return;                                   // block-uniform
    const uvec2* seg = fineSeg + (size_t)fid * CAP_F;

    // ---- T14: tuple prefetch issued BEFORE staging --------------------------
    const int hi = n - 1;
    uvec2 tp[3];
    #pragma unroll
    for (int k = 0; k < 3; ++k)
        tp[k] = __builtin_nontemporal_load(&seg[min(k * 128 + g, hi)]);

    // ---- cooperative DMA stage: 4 rounds x 512 threads of 16 B --------------
    #pragma unroll
    for (int k = 0; k < 4; ++k) {
        const int u  = k * 512 + t;
        const int uc = min(u, NUNITS - 1);             // tail -> pad units
        const int r  = uc >> 2, j = uc & 3;
        const int qs = (j + r) & 3;                    // source-side swizzle
        const int dx = r / 81, rem = r - dx * 81, dy = rem / 9, dz = rem - dy * 9;
        const int gx = min(gx0 + dx, 127);
        const int gy = min(gy0 + dy, 127);
        const int gz = min(gz0 + dz, 127);
        const float* src = latents
            + ((size_t)(((gx << 7) | gy) << 7 | gz)) * LATENT_DIM + qs * 4;
        float* dst = lat + (k * 512 + wave * 64) * 4;  // wave-uniform; HW adds lane*16B
        __builtin_amdgcn_global_load_lds((gptr_t)(const void*)src,
                                         (lptr_t)(void*)dst, 16, 0, 0);
    }

    __syncthreads();                                   // drains DMAs + tuples

    // ---- compute ------------------------------------------------------------
    #pragma unroll
    for (int k = 0; k < 3; ++k) {
        if (k * 128 + g < n) {
            const uvec2 tv = tp[k];
            const unsigned idx  = tv.x & 0x1FFFFFu;
            const unsigned cell = (tv.x >> 21) & 255u;
            const int rr0 = ((cell >> 6) & 3) * 81 + ((cell >> 3) & 7) * 9 + (cell & 7);

            const float wbx = (float)(tv.y & 4095u) * WQI;
            const float wby = (float)((tv.y >> 12) & 4095u) * WQI;
            const float wbz = (float)(((tv.x >> 29) & 7u) | (((tv.y >> 24) & 255u) << 3)) * WQI11;
            const float wax = 1.0f - wbx, way = 1.0f - wby, waz = 1.0f - wbz;
            const float fxy[4] = {wax * way, wax * wby, wbx * way, wbx * wby};
            const float fz[2]  = {waz, wbz};

            fvec4 acc = (fvec4)(0.0f);
            #pragma unroll
            for (int cc = 0; cc < 8; ++cc) {           // _OFFSETS order (x-major)
                const int ox = cc >> 2, oy = (cc >> 1) & 1, oz = cc & 1;
                const int rr = rr0 + ox * 81 + oy * 9 + oz;
                const int unit = rr * 4 + ((q - rr) & 3);
                const float w = fxy[ox * 2 + oy] * fz[oz];
                const fvec4 f = *reinterpret_cast<const fvec4*>(lat + unit * 4);
                acc += w * f;
            }

            __builtin_nontemporal_store(acc,
                reinterpret_cast<fvec4*>(out + (size_t)idx * LATENT_DIM + q * 4));
        }
    }
}

// ---- spill cleanup (normally n == 0; decodes packed super tuples) -----------

__global__ __launch_bounds__(256) void spillK(
    const uvec4* __restrict__ spillSeg, const unsigned* __restrict__ spillcur,
    const float* __restrict__ latents, float* __restrict__ out)
{
    const unsigned n = min(*spillcur, (unsigned)SPILL_CAP);
    for (unsigned i = blockIdx.x * 256 + threadIdx.x; i < n; i += gridDim.x * 256) {
        const uvec4 tp = spillSeg[i];
        const unsigned idx = tp.x & 0x1FFFFFu;
        const int lx = (tp.x >> 21) & 127, ly = tp.y & 127, lz = (tp.y >> 7) & 127;
        const float wbx = (float)((tp.y >> 14) & 4095u) * WQI;
        const float wby = (float)(tp.z & 4095u) * WQI;
        const float wbz = (float)((tp.z >> 12) & 4095u) * WQI;
        const int cx[2] = {lx, min(lx + 1, 127)};
        const int cy[2] = {ly, min(ly + 1, 127)};
        const int cz[2] = {lz, min(lz + 1, 127)};
        const float fx[2] = {1.0f - wbx, wbx};
        const float fy[2] = {1.0f - wby, wby};
        const float fz[2] = {1.0f - wbz, wbz};
        #pragma unroll
        for (int q = 0; q < 4; ++q) {
            const fvec4 acc = trilerp_q(latents, cx, cy, cz, fx, fy, fz, q);
            *reinterpret_cast<fvec4*>(out + (size_t)idx * LATENT_DIM + q * 4) = acc;
        }
    }
}

// ---- fallback: direct version ----------------------------------------------

__global__ __launch_bounds__(256) void trilerp_direct(
    const float* __restrict__ pts, const float* __restrict__ latents,
    float* __restrict__ out, int n_pts)
{
    const int tid = blockIdx.x * blockDim.x + threadIdx.x;
    const int p = tid >> 2;
    const int q = tid & 3;
    if (p >= n_pts) return;
    int cx[2], cy[2], cz[2]; float fx[2], fy[2], fz[2];
    corner_setup(pts[3*p] * SCALE, pts[3*p+1] * SCALE, pts[3*p+2] * SCALE,
                 cx, cy, cz, fx, fy, fz);
    const fvec4 acc = trilerp_q(latents, cx, cy, cz, fx, fy, fz, q);
    *reinterpret_cast<fvec4*>(out + (size_t)p * LATENT_DIM + q * 4) = acc;
}

// ---- launch -----------------------------------------------------------------

extern "C" void kernel_launch(void* const* d_in, const int* in_sizes, int n_in,
                              void* d_out, int out_size, void* d_ws, size_t ws_size,
                              hipStream_t stream) {
    const float* pts     = (const float*)d_in[0];
    const float* latents = (const float*)d_in[1];
    float* out = (float*)d_out;
    const int n_pts = in_sizes[0] / 3;

    const int cap_s = (int)(((size_t)out_size * 4) / (NSUPER * 16));  // tuples/super seg

    if (ws_size < WS_NEEDED || cap_s * (size_t)NSUPER * 16 > (size_t)out_size * 4 ||
        (size_t)cap_s < (size_t)n_pts / 128 || n_pts > (1 << 21)) {
        const int total = n_pts * 4;
        trilerp_direct<<<(total + 255) / 256, 256, 0, stream>>>(pts, latents, out, n_pts);
        return;
    }

    unsigned* scur     = (unsigned*)((char*)d_ws + SCUR_OFF);
    unsigned* fcur     = (unsigned*)((char*)d_ws + FCUR_OFF);
    unsigned* spillcur = (unsigned*)((char*)d_ws + SPILLCUR_OFF);
    uvec2*    fineSeg  = (uvec2*)((char*)d_ws + FINE_OFF);
    uvec4*    spillSeg = (uvec4*)((char*)d_ws + SPILL_OFF);
    uvec4*    superSeg = (uvec4*)d_out;                 // reused as scratch

    hipMemsetAsync(d_ws, 0, CUR_BYTES, stream);
    binA1<<<256, 256, 0, stream>>>(pts, n_pts, scur, superSeg, cap_s,
                                   spillcur, spillSeg);
    binA2<<<NSUPER * 4, 256, 0, stream>>>(superSeg, cap_s, scur,
                                          fcur, fineSeg, spillcur, spillSeg);
    binB<<<NFINE, 512, 0, stream>>>(fineSeg, fcur, latents, out);
    spillK<<<16, 256, 0, stream>>>(spillSeg, spillcur, latents, out);
}

// Round 19
// 102.337 us; speedup vs baseline: 1.0869x; 1.0869x over previous
//
#include <hip/hip_runtime.h>

// Trilinear interpolation of a 128^3 x 16 latent grid at 2M random points.
// 3-phase spatial counting sort; phase B = block-shared LDS tile.
//   A1: counting-sort points into 512 super-bins (16^3 cells); packed 16-B
//       tuples in d_out (fully overwritten by B afterwards).
//   A2: integer re-bin into 8 children (2x2x2 fine bins) -> 4096 fine bins
//       (8x8x8 cells each); 8-B packed tuples in d_ws.
//   B : one 512-thread block (8 waves) per fine bin; CUBIC tile 9x9x9 = 729
//       rows (48 KB incl. stage-tail pad) DMA-staged; overlap 1.42x vs 1.58x
//       cuts staging traffic 212->191 MB against the measured ~3.9 TB/s
//       scattered-VMEM wall; tuple prefetch BEFORE staging (T14); one
//       __syncthreads; 4 lanes/point; NT scatter stores.

constexpr int   GRID_RES   = 128;
constexpr int   LATENT_DIM = 16;
constexpr float SCALE      = 126.0f;          // GRID_RES - 2
constexpr float WQ         = 4095.0f;
constexpr float WQI        = 1.0f / 4095.0f;
constexpr float WQI10      = 1.0f / 1023.0f;

constexpr int NSUPER    = 512;                 // 8x8x8 supers of 16^3 cells
constexpr int NCHILD    = 8;                   // 2x2x2 fine bins per super
constexpr int NFINE     = NSUPER * NCHILD;     // 4096 = 16x16x16 bins
constexpr int CAP_F     = 640;                 // mean 512, sigma ~22.6
constexpr int SPILL_CAP = 16384;
constexpr int NROWS     = 9 * 9 * 9;           // 729 staged latent rows
constexpr int NUNITS    = NROWS * 4;           // 2916 16-B units
constexpr int NXCD      = 8;

// d_ws layout
constexpr size_t SCUR_OFF     = 0;             // 512 u32
constexpr size_t FCUR_OFF     = 2048;          // 4096 u32
constexpr size_t SPILLCUR_OFF = 18432;         // 1 u32
constexpr size_t CUR_BYTES    = 20480;         // memset region
constexpr size_t FINE_OFF     = CUR_BYTES;
constexpr size_t FINE_BYTES   = (size_t)NFINE * CAP_F * 8;    // 21 MB
constexpr size_t SPILL_OFF    = FINE_OFF + FINE_BYTES;
constexpr size_t WS_NEEDED    = SPILL_OFF + (size_t)SPILL_CAP * 16;

typedef float    fvec4 __attribute__((ext_vector_type(4)));
typedef unsigned uvec4 __attribute__((ext_vector_type(4)));
typedef unsigned uvec2 __attribute__((ext_vector_type(2)));
typedef const __attribute__((address_space(1))) unsigned int* gptr_t;
typedef __attribute__((address_space(3))) unsigned int*       lptr_t;

// ---- packing -----------------------------------------------------------------
// super tuple (uvec4): w0 = idx | lx<<21 ; w1 = ly | lz<<7 | wx12<<14 ;
//                      w2 = wy12 | wz12<<12 ; w3 = 0
// fine tuple (uvec2):  lo = idx | cell9<<21 | (wz10&3)<<30 ;
//                      hi = wx12 | wy12<<12 | (wz10>>2)<<24
// cell9 = (lx&7)<<6 | (ly&7)<<3 | (lz&7)   (bin = 8x8x8 cells)

__device__ __forceinline__ uvec4 pack_super(float x, float y, float z, unsigned idx) {
    const float sx = x * SCALE, sy = y * SCALE, sz = z * SCALE;
    const float bxf = floorf(sx), byf = floorf(sy), bzf = floorf(sz);
    const int lx = min(max((int)bxf, 0), 125);
    const int ly = min(max((int)byf, 0), 125);
    const int lz = min(max((int)bzf, 0), 125);
    const unsigned wx = (unsigned)rintf((sx - bxf) * WQ);
    const unsigned wy = (unsigned)rintf((sy - byf) * WQ);
    const unsigned wz = (unsigned)rintf((sz - bzf) * WQ);
    uvec4 t;
    t.x = idx | ((unsigned)lx << 21);
    t.y = (unsigned)ly | ((unsigned)lz << 7) | (wx << 14);
    t.z = wy | (wz << 12);
    t.w = 0u;
    return t;
}

__device__ __forceinline__ int super_of_xyz(float x, float y, float z) {
    const int lx = min(max((int)floorf(x * SCALE), 0), 125);
    const int ly = min(max((int)floorf(y * SCALE), 0), 125);
    const int lz = min(max((int)floorf(z * SCALE), 0), 125);
    return ((lx >> 4) << 6) | ((ly >> 4) << 3) | (lz >> 4);   // [0,512)
}

__device__ __forceinline__ int child_of(const uvec4 t) {
    const int lx = (t.x >> 21) & 127, ly = t.y & 127, lz = (t.y >> 7) & 127;
    return (((lx >> 3) & 1) << 2) | (((ly >> 3) & 1) << 1) | ((lz >> 3) & 1);  // [0,8)
}

__device__ __forceinline__ uvec2 pack_fine(const uvec4 t) {
    const int lx = (t.x >> 21) & 127, ly = t.y & 127, lz = (t.y >> 7) & 127;
    const unsigned cell = ((unsigned)(lx & 7) << 6) | ((unsigned)(ly & 7) << 3)
                        | (unsigned)(lz & 7);
    const unsigned wx = (t.y >> 14) & 4095u;
    const unsigned wy = t.z & 4095u;
    const unsigned wz12 = (t.z >> 12) & 4095u;
    const unsigned wz10 = min((wz12 + 2u) >> 2, 1023u);
    uvec2 f;
    f.x = (t.x & 0x1FFFFFu) | (cell << 21) | ((wz10 & 3u) << 30);
    f.y = wx | (wy << 12) | ((wz10 >> 2) << 24);
    return f;
}

// ---- shared helpers (spill/fallback trilerp) ----------------------------------

__device__ __forceinline__ void corner_setup(
    float sx, float sy, float sz,
    int cx[2], int cy[2], int cz[2],
    float fx[2], float fy[2], float fz[2])
{
    const float bx = floorf(sx), by = floorf(sy), bz = floorf(sz);
    const int ix = (int)bx, iy = (int)by, iz = (int)bz;
    const float wbx = sx - bx, wby = sy - by, wbz = sz - bz;
    cx[0] = min(max(ix,     0), GRID_RES - 1);
    cx[1] = min(max(ix + 1, 0), GRID_RES - 1);
    cy[0] = min(max(iy,     0), GRID_RES - 1);
    cy[1] = min(max(iy + 1, 0), GRID_RES - 1);
    cz[0] = min(max(iz,     0), GRID_RES - 1);
    cz[1] = min(max(iz + 1, 0), GRID_RES - 1);
    fx[0] = 1.0f - wbx; fx[1] = wbx;
    fy[0] = 1.0f - wby; fy[1] = wby;
    fz[0] = 1.0f - wbz; fz[1] = wbz;
}

__device__ __forceinline__ fvec4 trilerp_q(
    const float* __restrict__ latents,
    const int cx[2], const int cy[2], const int cz[2],
    const float fx[2], const float fy[2], const float fz[2], int q)
{
    fvec4 acc = (fvec4)(0.0f);
    #pragma unroll
    for (int ox = 0; ox < 2; ++ox)
      #pragma unroll
      for (int oy = 0; oy < 2; ++oy)
        #pragma unroll
        for (int oz = 0; oz < 2; ++oz) {
            const int flat = cx[ox] * (GRID_RES * GRID_RES) + cy[oy] * GRID_RES + cz[oz];
            const float w = fx[ox] * fy[oy] * fz[oz];
            const fvec4 f = *reinterpret_cast<const fvec4*>(
                latents + (size_t)flat * LATENT_DIM + q * 4);
            acc += w * f;
        }
    return acc;
}

// ---- A1: counting-sort into 512 super-bins (packed segments in d_out) -------

__global__ __launch_bounds__(256) void binA1(
    const float* __restrict__ pts, int n_pts,
    unsigned* __restrict__ scur, uvec4* __restrict__ superSeg, int cap_s,
    unsigned* __restrict__ spillcur, uvec4* __restrict__ spillSeg)
{
    __shared__ unsigned cnt[NSUPER], base[NSUPER], off[NSUPER];
    const int t = threadIdx.x;
    for (int i = t; i < NSUPER; i += 256) { cnt[i] = 0; off[i] = 0; }
    __syncthreads();

    int chunk = (n_pts + gridDim.x - 1) / gridDim.x;
    chunk = (chunk + 3) & ~3;                      // multiple of 4
    const int lo = blockIdx.x * chunk;
    const int hi = min(lo + chunk, n_pts);

    // ---- count pass (4 pts / thread, coalesced float4 loads) ----------------
    for (int p4 = lo + t * 4; p4 < hi; p4 += 1024) {
        if (p4 + 4 <= hi) {
            const fvec4 a = *reinterpret_cast<const fvec4*>(pts + (size_t)p4 * 3);
            const fvec4 b = *reinterpret_cast<const fvec4*>(pts + (size_t)p4 * 3 + 4);
            const fvec4 c = *reinterpret_cast<const fvec4*>(pts + (size_t)p4 * 3 + 8);
            atomicAdd(&cnt[super_of_xyz(a.x, a.y, a.z)], 1u);
            atomicAdd(&cnt[super_of_xyz(a.w, b.x, b.y)], 1u);
            atomicAdd(&cnt[super_of_xyz(b.z, b.w, c.x)], 1u);
            atomicAdd(&cnt[super_of_xyz(c.y, c.z, c.w)], 1u);
        } else {
            for (int p = p4; p < hi; ++p)
                atomicAdd(&cnt[super_of_xyz(pts[3*p], pts[3*p+1], pts[3*p+2])], 1u);
        }
    }
    __syncthreads();
    for (int i = t; i < NSUPER; i += 256) base[i] = atomicAdd(&scur[i], cnt[i]);
    __syncthreads();

    // ---- scatter pass -------------------------------------------------------
    auto emit = [&](float x, float y, float z, int p) {
        const int s = super_of_xyz(x, y, z);
        const unsigned slot = base[s] + atomicAdd(&off[s], 1u);
        const uvec4 tp = pack_super(x, y, z, (unsigned)p);
        if (slot < (unsigned)cap_s) {
            superSeg[(size_t)s * cap_s + slot] = tp;
        } else {
            const unsigned sp = atomicAdd(spillcur, 1u);
            if (sp < (unsigned)SPILL_CAP) spillSeg[sp] = tp;
        }
    };
    for (int p4 = lo + t * 4; p4 < hi; p4 += 1024) {
        if (p4 + 4 <= hi) {
            const fvec4 a = *reinterpret_cast<const fvec4*>(pts + (size_t)p4 * 3);
            const fvec4 b = *reinterpret_cast<const fvec4*>(pts + (size_t)p4 * 3 + 4);
            const fvec4 c = *reinterpret_cast<const fvec4*>(pts + (size_t)p4 * 3 + 8);
            emit(a.x, a.y, a.z, p4);
            emit(a.w, b.x, b.y, p4 + 1);
            emit(b.z, b.w, c.x, p4 + 2);
            emit(c.y, c.z, c.w, p4 + 3);
        } else {
            for (int p = p4; p < hi; ++p)
                emit(pts[3*p], pts[3*p+1], pts[3*p+2], p);
        }
    }
}

// ---- A2: integer re-bin into 8 children; write 8-B packed tuples ------------

__global__ __launch_bounds__(256) void binA2(
    const uvec4* __restrict__ superSeg, int cap_s,
    const unsigned* __restrict__ scur,
    unsigned* __restrict__ fcur, uvec2* __restrict__ fineSeg,
    unsigned* __restrict__ spillcur, uvec4* __restrict__ spillSeg)
{
    constexpr int SLICES = 8;
    const int super = blockIdx.x / SLICES;
    const int slice = blockIdx.x % SLICES;
    const unsigned n = min(scur[super], (unsigned)cap_s);
    const unsigned lo = (unsigned)(((unsigned long long)n * slice) / SLICES);
    const unsigned hi = (unsigned)(((unsigned long long)n * (slice + 1)) / SLICES);

    __shared__ unsigned cnt[NCHILD], base[NCHILD], off[NCHILD];
    const int t = threadIdx.x;
    if (t < NCHILD) { cnt[t] = 0; off[t] = 0; }
    __syncthreads();

    for (unsigned i = lo + t; i < hi; i += 256) {
        const uvec4 tp = superSeg[(size_t)super * cap_s + i];
        atomicAdd(&cnt[child_of(tp)], 1u);
    }
    __syncthreads();
    if (t < NCHILD) base[t] = atomicAdd(&fcur[super * NCHILD + t], cnt[t]);
    __syncthreads();
    for (unsigned i = lo + t; i < hi; i += 256) {
        const uvec4 tp = superSeg[(size_t)super * cap_s + i];
        const int c = child_of(tp);
        const unsigned slot = base[c] + atomicAdd(&off[c], 1u);
        if (slot < (unsigned)CAP_F) {
            fineSeg[(size_t)(super * NCHILD + c) * CAP_F + slot] = pack_fine(tp);
        } else {
            const unsigned sp = atomicAdd(spillcur, 1u);
            if (sp < (unsigned)SPILL_CAP) spillSeg[sp] = tp;
        }
    }
}

// ---- B: one 512-thread block (8 waves) per fine bin; cubic 9x9x9 tile -------
// 16-B unit u = rr*4 + ((q - rr) & 3); staging writes quarter qs=(j+r)&3 at
// unit (r,j) (inverse). rr = dx*81 + dy*9 + dz (z fastest -> 576-B runs).
// 48 KB LDS (incl. stage-tail pad) x 3 blocks/CU x 8 waves = 24 waves/CU.

__global__ __launch_bounds__(512, 6) void binB(
    const uvec2* __restrict__ fineSeg, const unsigned* __restrict__ fcur,
    const float* __restrict__ latents, float* __restrict__ out)
{
    __shared__ __align__(16) float lat[3072 * 4];   // 48 KB (2916 units + pad)

    const int orig = blockIdx.x;                    // 4096 blocks
    const int fid  = (orig & (NXCD - 1)) * (NFINE / NXCD) + (orig >> 3);

    const int t    = threadIdx.x;                   // [0,512)
    const int wave = t >> 6;
    const int q    = t & 3, g = t >> 2;             // q: quarter, g: point slot [0,128)

    const int s = fid >> 3, c = fid & 7;
    const int fbx = (((s >> 6) & 7) << 1) | ((c >> 2) & 1);   // [0,16)
    const int fby = (((s >> 3) & 7) << 1) | ((c >> 1) & 1);   // [0,16)
    const int fbz = ((s & 7) << 1)        | (c & 1);          // [0,16)
    const int gx0 = fbx * 8, gy0 = fby * 8, gz0 = fbz * 8;

    const int n = (int)min(fcur[fid], (unsigned)CAP_F);   // n <= 640 = 5*128
    if (n == 0) return;                                   // block-uniform
    const uvec2* seg = fineSeg + (size_t)fid * CAP_F;

    // ---- T14: tuple prefetch issued BEFORE staging --------------------------
    const int hi = n - 1;
    uvec2 tp[5];
    #pragma unroll
    for (int k = 0; k < 5; ++k)
        tp[k] = __builtin_nontemporal_load(&seg[min(k * 128 + g, hi)]);

    // ---- cooperative DMA stage: 6 rounds x 512 threads of 16 B --------------
    #pragma unroll
    for (int k = 0; k < 6; ++k) {
        const int u  = k * 512 + t;
        const int uc = min(u, NUNITS - 1);             // tail -> pad units
        const int r  = uc >> 2, j = uc & 3;
        const int qs = (j + r) & 3;                    // source-side swizzle
        const int dx = r / 81, rem = r - dx * 81, dy = rem / 9, dz = rem - dy * 9;
        const int gx = min(gx0 + dx, 127);
        const int gy = min(gy0 + dy, 127);
        const int gz = min(gz0 + dz, 127);
        const float* src = latents
            + ((size_t)(((gx << 7) | gy) << 7 | gz)) * LATENT_DIM + qs * 4;
        float* dst = lat + (k * 512 + wave * 64) * 4;  // wave-uniform; HW adds lane*16B
        __builtin_amdgcn_global_load_lds((gptr_t)(const void*)src,
                                         (lptr_t)(void*)dst, 16, 0, 0);
    }

    __syncthreads();                                   // drains DMAs + tuples

    // ---- compute ------------------------------------------------------------
    #pragma unroll
    for (int k = 0; k < 5; ++k) {
        if (k * 128 + g < n) {
            const uvec2 tv = tp[k];
            const unsigned idx  = tv.x & 0x1FFFFFu;
            const unsigned cell = (tv.x >> 21) & 511u;
            const int rr0 = ((cell >> 6) & 7) * 81 + ((cell >> 3) & 7) * 9 + (cell & 7);

            const float wbx = (float)(tv.y & 4095u) * WQI;
            const float wby = (float)((tv.y >> 12) & 4095u) * WQI;
            const float wbz = (float)(((tv.x >> 30) & 3u) | (((tv.y >> 24) & 255u) << 2)) * WQI10;
            const float wax = 1.0f - wbx, way = 1.0f - wby, waz = 1.0f - wbz;
            const float fxy[4] = {wax * way, wax * wby, wbx * way, wbx * wby};
            const float fz[2]  = {waz, wbz};

            fvec4 acc = (fvec4)(0.0f);
            #pragma unroll
            for (int cc = 0; cc < 8; ++cc) {           // _OFFSETS order (x-major)
                const int ox = cc >> 2, oy = (cc >> 1) & 1, oz = cc & 1;
                const int rr = rr0 + ox * 81 + oy * 9 + oz;
                const int unit = rr * 4 + ((q - rr) & 3);
                const float w = fxy[ox * 2 + oy] * fz[oz];
                const fvec4 f = *reinterpret_cast<const fvec4*>(lat + unit * 4);
                acc += w * f;
            }

            __builtin_nontemporal_store(acc,
                reinterpret_cast<fvec4*>(out + (size_t)idx * LATENT_DIM + q * 4));
        }
    }
}

// ---- spill cleanup (normally n == 0; decodes packed super tuples) -----------

__global__ __launch_bounds__(256) void spillK(
    const uvec4* __restrict__ spillSeg, const unsigned* __restrict__ spillcur,
    const float* __restrict__ latents, float* __restrict__ out)
{
    const unsigned n = min(*spillcur, (unsigned)SPILL_CAP);
    for (unsigned i = blockIdx.x * 256 + threadIdx.x; i < n; i += gridDim.x * 256) {
        const uvec4 tp = spillSeg[i];
        const unsigned idx = tp.x & 0x1FFFFFu;
        const int lx = (tp.x >> 21) & 127, ly = tp.y & 127, lz = (tp.y >> 7) & 127;
        const float wbx = (float)((tp.y >> 14) & 4095u) * WQI;
        const float wby = (float)(tp.z & 4095u) * WQI;
        const float wbz = (float)((tp.z >> 12) & 4095u) * WQI;
        const int cx[2] = {lx, min(lx + 1, 127)};
        const int cy[2] = {ly, min(ly + 1, 127)};
        const int cz[2] = {lz, min(lz + 1, 127)};
        const float fx[2] = {1.0f - wbx, wbx};
        const float fy[2] = {1.0f - wby, wby};
        const float fz[2] = {1.0f - wbz, wbz};
        #pragma unroll
        for (int q = 0; q < 4; ++q) {
            const fvec4 acc = trilerp_q(latents, cx, cy, cz, fx, fy, fz, q);
            *reinterpret_cast<fvec4*>(out + (size_t)idx * LATENT_DIM + q * 4) = acc;
        }
    }
}

// ---- fallback: direct version ----------------------------------------------

__global__ __launch_bounds__(256) void trilerp_direct(
    const float* __restrict__ pts, const float* __restrict__ latents,
    float* __restrict__ out, int n_pts)
{
    const int tid = blockIdx.x * blockDim.x + threadIdx.x;
    const int p = tid >> 2;
    const int q = tid & 3;
    if (p >= n_pts) return;
    int cx[2], cy[2], cz[2]; float fx[2], fy[2], fz[2];
    corner_setup(pts[3*p] * SCALE, pts[3*p+1] * SCALE, pts[3*p+2] * SCALE,
                 cx, cy, cz, fx, fy, fz);
    const fvec4 acc = trilerp_q(latents, cx, cy, cz, fx, fy, fz, q);
    *reinterpret_cast<fvec4*>(out + (size_t)p * LATENT_DIM + q * 4) = acc;
}

// ---- launch -----------------------------------------------------------------

extern "C" void kernel_launch(void* const* d_in, const int* in_sizes, int n_in,
                              void* d_out, int out_size, void* d_ws, size_t ws_size,
                              hipStream_t stream) {
    const float* pts     = (const float*)d_in[0];
    const float* latents = (const float*)d_in[1];
    float* out = (float*)d_out;
    const int n_pts = in_sizes[0] / 3;

    const int cap_s = (int)(((size_t)out_size * 4) / (NSUPER * 16));  // tuples/super seg

    if (ws_size < WS_NEEDED || cap_s * (size_t)NSUPER * 16 > (size_t)out_size * 4 ||
        (size_t)cap_s < (size_t)n_pts / 128 || n_pts > (1 << 21)) {
        const int total = n_pts * 4;
        trilerp_direct<<<(total + 255) / 256, 256, 0, stream>>>(pts, latents, out, n_pts);
        return;
    }

    unsigned* scur     = (unsigned*)((char*)d_ws + SCUR_OFF);
    unsigned* fcur     = (unsigned*)((char*)d_ws + FCUR_OFF);
    unsigned* spillcur = (unsigned*)((char*)d_ws + SPILLCUR_OFF);
    uvec2*    fineSeg  = (uvec2*)((char*)d_ws + FINE_OFF);
    uvec4*    spillSeg = (uvec4*)((char*)d_ws + SPILL_OFF);
    uvec4*    superSeg = (uvec4*)d_out;                 // reused as scratch

    hipMemsetAsync(d_ws, 0, CUR_BYTES, stream);
    binA1<<<256, 256, 0, stream>>>(pts, n_pts, scur, superSeg, cap_s,
                                   spillcur, spillSeg);
    binA2<<<NSUPER * 8, 256, 0, stream>>>(superSeg, cap_s, scur,
                                          fcur, fineSeg, spillcur, spillSeg);
    binB<<<NFINE, 512, 0, stream>>>(fineSeg, fcur, latents, out);
    spillK<<<16, 256, 0, stream>>>(spillSeg, spillcur, latents, out);
}